// Round 1
// baseline (600.073 us; speedup 1.0000x reference)
//
#include <hip/hip_runtime.h>

#define LAMBDA_FOR0 0.4f
#define LAMBDA_FOR1 1.6f
#define LOG_CLAMP  -100.0f

// 256 threads = 4 waves/block. 2048 blocks -> 8 blocks/CU on 256 CUs,
// full 32-wave occupancy for latency hiding on the streaming loads.
#define BLOCK 256
#define GRID  2048

__device__ __forceinline__ float elem_loss(float p, float t) {
    // log terms clamped at -100, exactly as torch BCELoss / reference.
    // __logf(0) = -inf -> fmaxf(-inf, -100) = -100 (correct).
    float log_p   = fmaxf(__logf(p), LOG_CLAMP);
    float log_1mp = fmaxf(log1pf(-p), LOG_CLAMP);
    float bce = -(t * log_p + (1.0f - t) * log_1mp);
    // reference: is_zero = (t == 0); weight 0.4 where zero else 1.6
    float w = (t == 0.0f) ? LAMBDA_FOR0 : LAMBDA_FOR1;
    return w * bce;
}

__global__ __launch_bounds__(BLOCK) void nbv_loss_kernel(
    const float* __restrict__ pred,
    const float* __restrict__ targ,
    float* __restrict__ out,
    long long n)
{
    const long long n4 = n >> 2;   // n is 2^26, divisible by 4
    const float4* __restrict__ p4 = (const float4*)pred;
    const float4* __restrict__ t4 = (const float4*)targ;

    long long idx    = (long long)blockIdx.x * BLOCK + threadIdx.x;
    long long stride = (long long)gridDim.x * BLOCK;

    float acc = 0.0f;
    for (long long i = idx; i < n4; i += stride) {
        float4 p = p4[i];
        float4 t = t4[i];
        acc += elem_loss(p.x, t.x);
        acc += elem_loss(p.y, t.y);
        acc += elem_loss(p.z, t.z);
        acc += elem_loss(p.w, t.w);
    }
    // scalar tail (defensive; n is divisible by 4 for this problem)
    for (long long i = n4 * 4 + idx; i < n; i += stride) {
        acc += elem_loss(pred[i], targ[i]);
    }

    // wave-64 butterfly reduction
    #pragma unroll
    for (int off = 32; off > 0; off >>= 1)
        acc += __shfl_down(acc, off, 64);

    // cross-wave reduction in LDS (4 waves/block)
    __shared__ float wsum[BLOCK / 64];
    int lane = threadIdx.x & 63;
    int wid  = threadIdx.x >> 6;
    if (lane == 0) wsum[wid] = acc;
    __syncthreads();

    if (wid == 0) {
        float blocksum = (lane < BLOCK / 64) ? wsum[lane] : 0.0f;
        #pragma unroll
        for (int off = 2; off > 0; off >>= 1)
            blocksum += __shfl_down(blocksum, off, 64);
        if (lane == 0)
            atomicAdd(out, blocksum);   // device-scope by default on gfx950
    }
}

extern "C" void kernel_launch(void* const* d_in, const int* in_sizes, int n_in,
                              void* d_out, int out_size, void* d_ws, size_t ws_size,
                              hipStream_t stream) {
    const float* pred = (const float*)d_in[0];
    const float* targ = (const float*)d_in[1];
    float* out = (float*)d_out;
    long long n = (long long)in_sizes[0];

    // d_out is re-poisoned to 0xAA before every timed replay: zero it here.
    hipMemsetAsync(out, 0, out_size * sizeof(float), stream);
    nbv_loss_kernel<<<GRID, BLOCK, 0, stream>>>(pred, targ, out, n);
}

// Round 2
// 508.485 us; speedup vs baseline: 1.1801x; 1.1801x over previous
//
#include <hip/hip_runtime.h>

#define LAMBDA_FOR0 0.4f
#define LAMBDA_FOR1 1.6f
#define LOG_CLAMP  -100.0f

// 256 threads = 4 waves/block. 2048 blocks -> 8 blocks/CU on 256 CUs.
#define BLOCK 256
#define GRID  2048

// target is exactly 0.0f or 1.0f, so
//   bce = (t==0) ? -log(1-p) : -log(p)     (each log clamped at -100)
//   loss = w * bce,  w = (t==0) ? 0.4 : 1.6
// Select the log ARGUMENT first -> one v_log_f32 per element (round 1 had
// __logf + libm log1pf = ~40 VALU ops/elem, VALUBusy 93%).
// 1-p is exact for p in [0.5,1) (Sterbenz), well-conditioned below.
__device__ __forceinline__ float elem_wlog(float p, float t) {
    bool  z  = (t == 0.0f);
    float pa = z ? (1.0f - p) : p;
    float w  = z ? LAMBDA_FOR0 : LAMBDA_FOR1;
    float lg = fmaxf(__logf(pa), LOG_CLAMP);   // __logf(0) = -inf -> -100
    return w * lg;
}

__global__ __launch_bounds__(BLOCK) void nbv_loss_kernel(
    const float* __restrict__ pred,
    const float* __restrict__ targ,
    float* __restrict__ out,
    long long n)
{
    const long long n4 = n >> 2;
    const float4* __restrict__ p4 = (const float4*)pred;
    const float4* __restrict__ t4 = (const float4*)targ;

    long long idx    = (long long)blockIdx.x * BLOCK + threadIdx.x;
    long long stride = (long long)gridDim.x * BLOCK;

    float acc = 0.0f;
    for (long long i = idx; i < n4; i += stride) {
        float4 p = p4[i];
        float4 t = t4[i];
        acc += elem_wlog(p.x, t.x);
        acc += elem_wlog(p.y, t.y);
        acc += elem_wlog(p.z, t.z);
        acc += elem_wlog(p.w, t.w);
    }
    // scalar tail (defensive; n = 2^26 is divisible by 4)
    for (long long i = n4 * 4 + idx; i < n; i += stride) {
        acc += elem_wlog(pred[i], targ[i]);
    }

    // wave-64 butterfly reduction
    #pragma unroll
    for (int off = 32; off > 0; off >>= 1)
        acc += __shfl_down(acc, off, 64);

    // cross-wave reduction in LDS (4 waves/block)
    __shared__ float wsum[BLOCK / 64];
    int lane = threadIdx.x & 63;
    int wid  = threadIdx.x >> 6;
    if (lane == 0) wsum[wid] = acc;
    __syncthreads();

    if (wid == 0) {
        float blocksum = (lane < BLOCK / 64) ? wsum[lane] : 0.0f;
        #pragma unroll
        for (int off = 2; off > 0; off >>= 1)
            blocksum += __shfl_down(blocksum, off, 64);
        if (lane == 0)
            atomicAdd(out, -blocksum);   // single negate: loss = -sum(w*log)
    }
}

extern "C" void kernel_launch(void* const* d_in, const int* in_sizes, int n_in,
                              void* d_out, int out_size, void* d_ws, size_t ws_size,
                              hipStream_t stream) {
    const float* pred = (const float*)d_in[0];
    const float* targ = (const float*)d_in[1];
    float* out = (float*)d_out;
    long long n = (long long)in_sizes[0];

    // d_out is re-poisoned to 0xAA before every timed replay: zero it here.
    hipMemsetAsync(out, 0, out_size * sizeof(float), stream);
    nbv_loss_kernel<<<GRID, BLOCK, 0, stream>>>(pred, targ, out, n);
}

// Round 3
// 500.487 us; speedup vs baseline: 1.1990x; 1.0160x over previous
//
#include <hip/hip_runtime.h>

#define LAMBDA_FOR0 0.4f
#define LAMBDA_FOR1 1.6f
#define LOG_CLAMP  -100.0f

#define BLOCK 256   // 4 waves/block
#define GRID  2048  // 8 blocks/CU on 256 CUs -> 32 waves/CU (max occupancy)

// target is exactly 0.0f or 1.0f:
//   loss_elem = w * (-log(arg)),  arg = (t==0) ? 1-p : p,  w = (t==0)?0.4:1.6
// One v_log_f32 per element; log clamped at -100 (__logf(0)=-inf -> fmaxf).
__device__ __forceinline__ float elem_wlog(float p, float t) {
    bool  z  = (t == 0.0f);
    float pa = z ? (1.0f - p) : p;
    float w  = z ? LAMBDA_FOR0 : LAMBDA_FOR1;
    float lg = fmaxf(__logf(pa), LOG_CLAMP);
    return w * lg;
}

__device__ __forceinline__ float wlog4(float4 p, float4 t) {
    return elem_wlog(p.x, t.x) + elem_wlog(p.y, t.y)
         + elem_wlog(p.z, t.z) + elem_wlog(p.w, t.w);
}

// Stage 1: grid-stride over float4s, per-block partial -> partials[blockIdx].
// Plain store overwrites the 0xAA poison in d_ws; no memset / atomics needed.
__global__ __launch_bounds__(BLOCK) void nbv_partial_kernel(
    const float* __restrict__ pred,
    const float* __restrict__ targ,
    float* __restrict__ partials,
    long long n)
{
    const long long n4 = n >> 2;
    const float4* __restrict__ p4 = (const float4*)pred;
    const float4* __restrict__ t4 = (const float4*)targ;

    const long long idx    = (long long)blockIdx.x * BLOCK + threadIdx.x;
    const long long stride = (long long)gridDim.x * BLOCK;

    float acc = 0.0f;
    long long i = idx;
    // unroll x2: two independent float4 pairs in flight per iteration
    for (; i + stride < n4; i += 2 * stride) {
        float4 pa = p4[i];          float4 ta = t4[i];
        float4 pb = p4[i + stride]; float4 tb = t4[i + stride];
        acc += wlog4(pa, ta);
        acc += wlog4(pb, tb);
    }
    for (; i < n4; i += stride) {
        acc += wlog4(p4[i], t4[i]);
    }
    // scalar tail (defensive; n = 2^26 is divisible by 4)
    for (long long j = n4 * 4 + idx; j < n; j += stride) {
        acc += elem_wlog(pred[j], targ[j]);
    }

    // wave-64 reduction
    #pragma unroll
    for (int off = 32; off > 0; off >>= 1)
        acc += __shfl_down(acc, off, 64);

    __shared__ float wsum[BLOCK / 64];
    const int lane = threadIdx.x & 63;
    const int wid  = threadIdx.x >> 6;
    if (lane == 0) wsum[wid] = acc;
    __syncthreads();

    if (wid == 0) {
        float blocksum = (lane < BLOCK / 64) ? wsum[lane] : 0.0f;
        #pragma unroll
        for (int off = 2; off > 0; off >>= 1)
            blocksum += __shfl_down(blocksum, off, 64);
        if (lane == 0) partials[blockIdx.x] = blocksum;
    }
}

// Stage 2: one block reduces GRID partials, plain-stores final (negated) loss.
__global__ __launch_bounds__(BLOCK) void nbv_final_kernel(
    const float* __restrict__ partials,
    float* __restrict__ out)
{
    float acc = 0.0f;
    for (int i = threadIdx.x; i < GRID; i += BLOCK)
        acc += partials[i];

    #pragma unroll
    for (int off = 32; off > 0; off >>= 1)
        acc += __shfl_down(acc, off, 64);

    __shared__ float wsum[BLOCK / 64];
    const int lane = threadIdx.x & 63;
    const int wid  = threadIdx.x >> 6;
    if (lane == 0) wsum[wid] = acc;
    __syncthreads();

    if (threadIdx.x == 0) {
        float s = 0.0f;
        #pragma unroll
        for (int k = 0; k < BLOCK / 64; ++k) s += wsum[k];
        *out = -s;   // loss = -sum(w * log)
    }
}

extern "C" void kernel_launch(void* const* d_in, const int* in_sizes, int n_in,
                              void* d_out, int out_size, void* d_ws, size_t ws_size,
                              hipStream_t stream) {
    const float* pred = (const float*)d_in[0];
    const float* targ = (const float*)d_in[1];
    float* out      = (float*)d_out;
    float* partials = (float*)d_ws;   // GRID floats = 8 KiB scratch
    long long n = (long long)in_sizes[0];

    nbv_partial_kernel<<<GRID, BLOCK, 0, stream>>>(pred, targ, partials, n);
    nbv_final_kernel<<<1, BLOCK, 0, stream>>>(partials, out);
}

// Round 5
// 478.452 us; speedup vs baseline: 1.2542x; 1.0461x over previous
//
#include <hip/hip_runtime.h>

#define LAMBDA_FOR0 0.4f
#define LAMBDA_FOR1 1.6f
#define LOG_CLAMP  -100.0f

#define BLOCK 256   // 4 waves/block
#define GRID  2048  // 8 blocks/CU on 256 CUs -> 32 waves/CU (max occupancy)
#define UNROLL 4

// Native vector type: __builtin_nontemporal_load rejects HIP's float4 class,
// but accepts a Clang ext_vector_type. Same 16B global_load_dwordx4 (+nt).
typedef float f32x4 __attribute__((ext_vector_type(4)));

// target is exactly 0.0f or 1.0f:
//   loss_elem = w * (-log(arg)),  arg = (t==0) ? 1-p : p,  w = (t==0)?0.4:1.6
// One v_log_f32 per element; log clamped at -100 (__logf(0)=-inf -> fmaxf).
__device__ __forceinline__ float elem_wlog(float p, float t) {
    bool  z  = (t == 0.0f);
    float pa = z ? (1.0f - p) : p;
    float w  = z ? LAMBDA_FOR0 : LAMBDA_FOR1;
    float lg = fmaxf(__logf(pa), LOG_CLAMP);
    return w * lg;
}

__device__ __forceinline__ float wlog4(f32x4 p, f32x4 t) {
    return elem_wlog(p.x, t.x) + elem_wlog(p.y, t.y)
         + elem_wlog(p.z, t.z) + elem_wlog(p.w, t.w);
}

// Stage 1: grid-stride over float4s; all UNROLL*2 loads issued before any
// compute (128 B in flight/thread) to hide ~900-cyc HBM miss latency.
__global__ __launch_bounds__(BLOCK) void nbv_partial_kernel(
    const float* __restrict__ pred,
    const float* __restrict__ targ,
    float* __restrict__ partials,
    long long n)
{
    const long long n4 = n >> 2;
    const f32x4* __restrict__ p4 = (const f32x4*)pred;
    const f32x4* __restrict__ t4 = (const f32x4*)targ;

    const long long idx    = (long long)blockIdx.x * BLOCK + threadIdx.x;
    const long long stride = (long long)gridDim.x * BLOCK;

    float acc = 0.0f;
    long long i = idx;

    // main: UNROLL independent float4-pairs per iteration, loads batched first
    for (; i + (UNROLL - 1) * stride < n4; i += UNROLL * stride) {
        f32x4 p[UNROLL], t[UNROLL];
        #pragma unroll
        for (int u = 0; u < UNROLL; ++u)
            p[u] = __builtin_nontemporal_load(&p4[i + u * stride]);
        #pragma unroll
        for (int u = 0; u < UNROLL; ++u)
            t[u] = __builtin_nontemporal_load(&t4[i + u * stride]);
        #pragma unroll
        for (int u = 0; u < UNROLL; ++u)
            acc += wlog4(p[u], t[u]);
    }
    // remainder float4s
    for (; i < n4; i += stride) {
        f32x4 p = __builtin_nontemporal_load(&p4[i]);
        f32x4 t = __builtin_nontemporal_load(&t4[i]);
        acc += wlog4(p, t);
    }
    // scalar tail (defensive; n = 2^26 is divisible by 4)
    for (long long j = n4 * 4 + idx; j < n; j += stride) {
        acc += elem_wlog(pred[j], targ[j]);
    }

    // wave-64 reduction
    #pragma unroll
    for (int off = 32; off > 0; off >>= 1)
        acc += __shfl_down(acc, off, 64);

    __shared__ float wsum[BLOCK / 64];
    const int lane = threadIdx.x & 63;
    const int wid  = threadIdx.x >> 6;
    if (lane == 0) wsum[wid] = acc;
    __syncthreads();

    if (wid == 0) {
        float blocksum = (lane < BLOCK / 64) ? wsum[lane] : 0.0f;
        #pragma unroll
        for (int off = 2; off > 0; off >>= 1)
            blocksum += __shfl_down(blocksum, off, 64);
        if (lane == 0) partials[blockIdx.x] = blocksum;
    }
}

// Stage 2: one block reduces GRID partials, plain-stores final (negated) loss.
__global__ __launch_bounds__(BLOCK) void nbv_final_kernel(
    const float* __restrict__ partials,
    float* __restrict__ out)
{
    float acc = 0.0f;
    for (int i = threadIdx.x; i < GRID; i += BLOCK)
        acc += partials[i];

    #pragma unroll
    for (int off = 32; off > 0; off >>= 1)
        acc += __shfl_down(acc, off, 64);

    __shared__ float wsum[BLOCK / 64];
    const int lane = threadIdx.x & 63;
    const int wid  = threadIdx.x >> 6;
    if (lane == 0) wsum[wid] = acc;
    __syncthreads();

    if (threadIdx.x == 0) {
        float s = 0.0f;
        #pragma unroll
        for (int k = 0; k < BLOCK / 64; ++k) s += wsum[k];
        *out = -s;   // loss = -sum(w * log)
    }
}

extern "C" void kernel_launch(void* const* d_in, const int* in_sizes, int n_in,
                              void* d_out, int out_size, void* d_ws, size_t ws_size,
                              hipStream_t stream) {
    const float* pred = (const float*)d_in[0];
    const float* targ = (const float*)d_in[1];
    float* out      = (float*)d_out;
    float* partials = (float*)d_ws;   // GRID floats = 8 KiB scratch
    long long n = (long long)in_sizes[0];

    nbv_partial_kernel<<<GRID, BLOCK, 0, stream>>>(pred, targ, partials, n);
    nbv_final_kernel<<<1, BLOCK, 0, stream>>>(partials, out);
}